// Round 1
// baseline (2474.572 us; speedup 1.0000x reference)
//
#include <hip/hip_runtime.h>
#include <cstddef>

// ---------------------------------------------------------------------------
// Generic tiled submanifold sparse conv:
//   out[n, co] = sum_{k=0..26} sum_ci fpad[nbr[n,k], ci] * (att?att[nbr]:1) * W[k, ci, co]
// Tile of TILE sites staged in LDS per offset k; each thread computes TS sites
// x TCO output channels in registers. fp32 throughout (score chain must stay
// fp32-accurate: masks are hard thresholds).
// ---------------------------------------------------------------------------
template<int C, int CO, int TILE, int TS, int TCO>
__global__ __launch_bounds__((CO / TCO) * (TILE / TS))
void subm_conv_kernel(const float* __restrict__ f,
                      const float* __restrict__ att,   // nullable per-row scale
                      const int* __restrict__ nbr,     // [N, 27]
                      const float* __restrict__ W,     // [27, C, CO]
                      float* __restrict__ out,         // [N, CO]
                      int N)
{
    constexpr int CO_GRP = CO / TCO;
    constexpr int S_GRP  = TILE / TS;
    constexpr int NT     = CO_GRP * S_GRP;
    static_assert(C % 4 == 0, "C must be multiple of 4");

    __shared__ float lds[TILE][C];
    __shared__ int   snbr[TILE * 27];

    const int tid   = threadIdx.x;
    const int cogrp = tid % CO_GRP;
    const int sgrp  = tid / CO_GRP;
    const int n0    = blockIdx.x * TILE;

    // Preload the neighbor table for this tile (coalesced, layout-identical).
    for (int e = tid; e < TILE * 27; e += NT) {
        const int n = n0 + e / 27;
        snbr[e] = (n < N) ? nbr[(size_t)n * 27 + (e % 27)] : -1;
    }

    float acc[TS][TCO];
#pragma unroll
    for (int s = 0; s < TS; ++s)
#pragma unroll
        for (int c = 0; c < TCO; ++c)
            acc[s][c] = 0.f;

    for (int k = 0; k < 27; ++k) {
        __syncthreads();  // also covers snbr preload at k==0
        // Gather TILE neighbor rows into LDS (zero row if absent), fuse att scale.
        for (int e = tid; e < TILE * (C / 4); e += NT) {
            const int r   = e / (C / 4);
            const int c4  = e % (C / 4);
            const int idx = snbr[r * 27 + k];
            float4 v = make_float4(0.f, 0.f, 0.f, 0.f);
            if (idx >= 0) {
                v = *reinterpret_cast<const float4*>(f + (size_t)idx * C + c4 * 4);
                if (att != nullptr) {
                    const float a = att[idx];
                    v.x *= a; v.y *= a; v.z *= a; v.w *= a;
                }
            }
            *reinterpret_cast<float4*>(&lds[r][c4 * 4]) = v;
        }
        __syncthreads();

        const float* __restrict__ Wk = W + (size_t)k * C * CO;
        for (int ci = 0; ci < C; ci += 4) {
            float4 fv[TS];
#pragma unroll
            for (int s = 0; s < TS; ++s)
                fv[s] = *reinterpret_cast<const float4*>(&lds[sgrp * TS + s][ci]);
#pragma unroll
            for (int j = 0; j < 4; ++j) {
                const float* wp = Wk + (size_t)(ci + j) * CO + cogrp * TCO;
                if constexpr (TCO == 4) {
                    const float4 w4 = *reinterpret_cast<const float4*>(wp);
#pragma unroll
                    for (int s = 0; s < TS; ++s) {
                        const float fs = (j == 0) ? fv[s].x : (j == 1) ? fv[s].y
                                       : (j == 2) ? fv[s].z : fv[s].w;
                        acc[s][0] = fmaf(fs, w4.x, acc[s][0]);
                        acc[s][1] = fmaf(fs, w4.y, acc[s][1]);
                        acc[s][2] = fmaf(fs, w4.z, acc[s][2]);
                        acc[s][3] = fmaf(fs, w4.w, acc[s][3]);
                    }
                } else {  // TCO == 2
                    const float2 w2 = *reinterpret_cast<const float2*>(wp);
#pragma unroll
                    for (int s = 0; s < TS; ++s) {
                        const float fs = (j == 0) ? fv[s].x : (j == 1) ? fv[s].y
                                       : (j == 2) ? fv[s].z : fv[s].w;
                        acc[s][0] = fmaf(fs, w2.x, acc[s][0]);
                        acc[s][1] = fmaf(fs, w2.y, acc[s][1]);
                    }
                }
            }
        }
    }

#pragma unroll
    for (int s = 0; s < TS; ++s) {
        const int n = n0 + sgrp * TS + s;
        if (n < N) {
            float* op = out + (size_t)n * CO + cogrp * TCO;
            if constexpr (TCO == 4)
                *reinterpret_cast<float4*>(op) = make_float4(acc[s][0], acc[s][1], acc[s][2], acc[s][3]);
            else
                *reinterpret_cast<float2*>(op) = make_float2(acc[s][0], acc[s][1]);
        }
    }
}

// ---------------------------------------------------------------------------
// Score conv (CO=2): one wave per site, lanes over input channels, shuffle
// reduce. Also fills the coords columns of the ppn output rows [coords|s0 s1].
// ---------------------------------------------------------------------------
template<int C>
__global__ __launch_bounds__(256)
void score_kernel(const float* __restrict__ x,
                  const int* __restrict__ nbr,
                  const float* __restrict__ W,       // [27, C, 2]
                  const int* __restrict__ coords,    // [N, 4]
                  float* __restrict__ ppn,           // [N, 6]
                  int N)
{
    const int lane = threadIdx.x & 63;
    const int wid  = threadIdx.x >> 6;
    const int site = blockIdx.x * (blockDim.x >> 6) + wid;
    if (site >= N) return;

    float a0 = 0.f, a1 = 0.f;
    for (int k = 0; k < 27; ++k) {
        const int idx = nbr[(size_t)site * 27 + k];
        if (idx < 0) continue;
        const float* xr = x + (size_t)idx * C;
        const float* Wk = W + (size_t)k * C * 2;
#pragma unroll
        for (int ci0 = 0; ci0 < C; ci0 += 64) {
            const int ci = ci0 + lane;
            if (C % 64 == 0 || ci < C) {
                const float xv = xr[ci];
                a0 = fmaf(xv, Wk[ci * 2 + 0], a0);
                a1 = fmaf(xv, Wk[ci * 2 + 1], a1);
            }
        }
    }
#pragma unroll
    for (int off = 32; off; off >>= 1) {
        a0 += __shfl_down(a0, off, 64);
        a1 += __shfl_down(a1, off, 64);
    }
    if (lane == 0) {
        ppn[(size_t)site * 6 + 4] = a0;
        ppn[(size_t)site * 6 + 5] = a1;
    }
    if (lane < 4) ppn[(size_t)site * 6 + lane] = (float)coords[(size_t)site * 4 + lane];
}

// ---------------------------------------------------------------------------
// attention[i] = (softmax(scores[parent[i]])[1] > 0.8) ? 1 : 0
// scores read from the ppn output rows (cols 4,5). Same softmax formula as
// jax.nn.softmax to keep threshold boundary behavior aligned.
// ---------------------------------------------------------------------------
__global__ __launch_bounds__(256)
void att_kernel(const float* __restrict__ ppn, const int* __restrict__ parent,
                float* __restrict__ att, int N)
{
    const int i = blockIdx.x * blockDim.x + threadIdx.x;
    if (i >= N) return;
    const int p = parent[i];
    const float s0 = ppn[(size_t)p * 6 + 4];
    const float s1 = ppn[(size_t)p * 6 + 5];
    const float m  = fmaxf(s0, s1);
    const float e0 = expf(s0 - m);
    const float e1 = expf(s1 - m);
    const float p1 = e1 / (e0 + e1);
    att[i] = (p1 > 0.8f) ? 1.f : 0.f;
}

// Pack the three head weights [27,32,{3,2,5}] into one [27,32,10] buffer so
// the three head convs fuse into a single conv pass over z.
__global__ __launch_bounds__(256)
void pack_head_w(const float* __restrict__ wp, const float* __restrict__ ws,
                 const float* __restrict__ wt, float* __restrict__ Wh)
{
    const int i = blockIdx.x * blockDim.x + threadIdx.x;
    if (i >= 27 * 32 * 10) return;
    const int co = i % 10;
    const int ci = (i / 10) % 32;
    const int k  = i / 320;
    float v;
    if (co < 3)      v = wp[(k * 32 + ci) * 3 + co];
    else if (co < 5) v = ws[(k * 32 + ci) * 2 + (co - 3)];
    else             v = wt[(k * 32 + ci) * 5 + (co - 5)];
    Wh[i] = v;
}

extern "C" void kernel_launch(void* const* d_in, const int* in_sizes, int n_in,
                              void* d_out, int out_size, void* d_ws, size_t ws_size,
                              hipStream_t stream)
{
    const float* f1       = (const float*)d_in[0];
    const float* f2       = (const float*)d_in[1];
    const float* f3       = (const float*)d_in[2];
    const float* w1_conv  = (const float*)d_in[3];
    const float* w1_score = (const float*)d_in[4];
    const float* w2_conv  = (const float*)d_in[5];
    const float* w2_score = (const float*)d_in[6];
    const float* w3_conv  = (const float*)d_in[7];
    const float* w3_pix   = (const float*)d_in[8];
    const float* w3_score = (const float*)d_in[9];
    const float* w3_type  = (const float*)d_in[10];
    const int* coords1    = (const int*)d_in[11];
    const int* coords2    = (const int*)d_in[12];
    const int* nbr1       = (const int*)d_in[13];
    const int* nbr2       = (const int*)d_in[14];
    const int* nbr3       = (const int*)d_in[15];
    const int* parent12   = (const int*)d_in[16];
    const int* parent23   = (const int*)d_in[17];

    const int N1 = in_sizes[0] / 160;   // 20000,  C1 = 160
    const int N2 = in_sizes[1] / 96;    // 160000, C2 = 96
    const int N3 = in_sizes[2] / 32;    // 320000, C3 = 32

    // Output layout (flat, return order): points[N3,10] | ppn1[N1,6] |
    // ppn2[N2,6] | att[N2] | att2[N3]
    float* outf   = (float*)d_out;
    float* points = outf;
    float* ppn1   = points + (size_t)N3 * 10;
    float* ppn2   = ppn1 + (size_t)N1 * 6;
    float* attn   = ppn2 + (size_t)N2 * 6;
    float* attn2  = attn + (size_t)N2;

    // Workspace: one reused feature buffer (x -> y -> z) + packed head weights.
    float* buf = (float*)d_ws;
    size_t bufElems = (size_t)N1 * 160;
    if ((size_t)N2 * 96 > bufElems) bufElems = (size_t)N2 * 96;
    if ((size_t)N3 * 32 > bufElems) bufElems = (size_t)N3 * 32;
    float* Wh = buf + bufElems;

    pack_head_w<<<(27 * 32 * 10 + 255) / 256, 256, 0, stream>>>(w3_pix, w3_score, w3_type, Wh);

    // ---- level 1 (stride 4) ----
    subm_conv_kernel<160, 160, 32, 4, 4>
        <<<(N1 + 31) / 32, (160 / 4) * (32 / 4), 0, stream>>>(f1, nullptr, nbr1, w1_conv, buf, N1);
    score_kernel<160><<<(N1 + 3) / 4, 256, 0, stream>>>(buf, nbr1, w1_score, coords1, ppn1, N1);
    att_kernel<<<(N2 + 255) / 256, 256, 0, stream>>>(ppn1, parent12, attn, N2);

    // ---- level 2 (stride 2) ----
    subm_conv_kernel<96, 96, 64, 8, 4>
        <<<(N2 + 63) / 64, (96 / 4) * (64 / 8), 0, stream>>>(f2, attn, nbr2, w2_conv, buf, N2);
    score_kernel<96><<<(N2 + 3) / 4, 256, 0, stream>>>(buf, nbr2, w2_score, coords2, ppn2, N2);
    att_kernel<<<(N3 + 255) / 256, 256, 0, stream>>>(ppn2, parent23, attn2, N3);

    // ---- level 3 (full res) ----
    subm_conv_kernel<32, 32, 128, 8, 4>
        <<<(N3 + 127) / 128, (32 / 4) * (128 / 8), 0, stream>>>(f3, attn2, nbr3, w3_conv, buf, N3);
    subm_conv_kernel<32, 10, 128, 4, 2>
        <<<(N3 + 127) / 128, (10 / 2) * (128 / 4), 0, stream>>>(buf, nullptr, nbr3, Wh, points, N3);
}

// Round 2
// 2403.942 us; speedup vs baseline: 1.0294x; 1.0294x over previous
//
#include <hip/hip_runtime.h>
#include <cstddef>

typedef short bf16x8 __attribute__((ext_vector_type(8)));
typedef float f32x4 __attribute__((ext_vector_type(4)));

__device__ inline unsigned short f2bf(float x) {
    unsigned u = __builtin_bit_cast(unsigned, x);
    u += 0x7fffu + ((u >> 16) & 1u);   // round-to-nearest-even
    return (unsigned short)(u >> 16);
}

// ---------------------------------------------------------------------------
// fp32 tiled submanifold conv (mask-feeding levels must stay fp32-exact).
// Bank-conflict-free: LDS row stride C+4 (mod 32 = 4) and lanes of a wave
// read CONSECUTIVE rows (site = s*S_GRP + sgrp). Neighbor indices prefetched
// into registers for next k during the compute phase (no snbr LDS -> better
// occupancy).
// ---------------------------------------------------------------------------
template<int C, int CO, int TILE, int TS, int TCO>
__global__ __launch_bounds__((CO / TCO) * (TILE / TS))
void subm_conv_kernel(const float* __restrict__ f,
                      const float* __restrict__ att,   // nullable per-row scale
                      const int* __restrict__ nbr,     // [N, 27]
                      const float* __restrict__ W,     // [27, C, CO]
                      float* __restrict__ out,         // [N, CO]
                      int N)
{
    constexpr int CO_GRP = CO / TCO;
    constexpr int S_GRP  = TILE / TS;
    constexpr int NT     = CO_GRP * S_GRP;
    constexpr int STRIDE = C + 4;                 // mod 32 == 4 -> conflict-free
    constexpr int NITEM  = (TILE * (C / 4)) / NT; // gather items per thread
    static_assert((TILE * (C / 4)) % NT == 0, "gather must divide evenly");
    static_assert(C % 4 == 0, "C must be multiple of 4");

    __shared__ float lds[TILE * STRIDE];

    const int tid   = threadIdx.x;
    const int cogrp = tid % CO_GRP;
    const int sgrp  = tid / CO_GRP;
    const int n0    = blockIdx.x * TILE;

    int rowi[NITEM], idx[NITEM];
#pragma unroll
    for (int i = 0; i < NITEM; ++i)
        rowi[i] = (tid + i * NT) / (C / 4);
#pragma unroll
    for (int i = 0; i < NITEM; ++i) {
        const int n = n0 + rowi[i];
        idx[i] = (n < N) ? nbr[(size_t)n * 27] : -1;
    }

    float acc[TS][TCO] = {};

    for (int k = 0; k < 27; ++k) {
        __syncthreads();   // previous compute done reading lds
        // Gather TILE rows (zero for missing neighbor), fused att scale.
#pragma unroll
        for (int i = 0; i < NITEM; ++i) {
            const int e  = tid + i * NT;
            const int r  = rowi[i];
            const int c4 = e % (C / 4);
            const int id = idx[i];
            float4 v = make_float4(0.f, 0.f, 0.f, 0.f);
            if (id >= 0) {
                v = *reinterpret_cast<const float4*>(f + (size_t)id * C + c4 * 4);
                if (att != nullptr) {
                    const float a = att[id];
                    v.x *= a; v.y *= a; v.z *= a; v.w *= a;
                }
            }
            *reinterpret_cast<float4*>(&lds[r * STRIDE + c4 * 4]) = v;
        }
        __syncthreads();
        // Prefetch next k's neighbor indices; latency hides under FMAs.
        if (k + 1 < 27) {
#pragma unroll
            for (int i = 0; i < NITEM; ++i) {
                const int n = n0 + rowi[i];
                idx[i] = (n < N) ? nbr[(size_t)n * 27 + (k + 1)] : -1;
            }
        }

        const float* __restrict__ Wk = W + (size_t)k * C * CO;
        for (int ci = 0; ci < C; ci += 4) {
            float4 fv[TS];
#pragma unroll
            for (int s = 0; s < TS; ++s)
                fv[s] = *reinterpret_cast<const float4*>(&lds[(s * S_GRP + sgrp) * STRIDE + ci]);
#pragma unroll
            for (int j = 0; j < 4; ++j) {
                const float* wp = Wk + (size_t)(ci + j) * CO + cogrp * TCO;
                if constexpr (TCO == 4) {
                    const float4 w4 = *reinterpret_cast<const float4*>(wp);
#pragma unroll
                    for (int s = 0; s < TS; ++s) {
                        const float fs = (j == 0) ? fv[s].x : (j == 1) ? fv[s].y
                                       : (j == 2) ? fv[s].z : fv[s].w;
                        acc[s][0] = fmaf(fs, w4.x, acc[s][0]);
                        acc[s][1] = fmaf(fs, w4.y, acc[s][1]);
                        acc[s][2] = fmaf(fs, w4.z, acc[s][2]);
                        acc[s][3] = fmaf(fs, w4.w, acc[s][3]);
                    }
                } else {  // TCO == 2
                    const float2 w2 = *reinterpret_cast<const float2*>(wp);
#pragma unroll
                    for (int s = 0; s < TS; ++s) {
                        const float fs = (j == 0) ? fv[s].x : (j == 1) ? fv[s].y
                                       : (j == 2) ? fv[s].z : fv[s].w;
                        acc[s][0] = fmaf(fs, w2.x, acc[s][0]);
                        acc[s][1] = fmaf(fs, w2.y, acc[s][1]);
                    }
                }
            }
        }
    }

#pragma unroll
    for (int s = 0; s < TS; ++s) {
        const int n = n0 + s * S_GRP + sgrp;
        if (n < N) {
            float* op = out + (size_t)n * CO + cogrp * TCO;
            if constexpr (TCO == 4)
                *reinterpret_cast<float4*>(op) = make_float4(acc[s][0], acc[s][1], acc[s][2], acc[s][3]);
            else
                *reinterpret_cast<float2*>(op) = make_float2(acc[s][0], acc[s][1]);
        }
    }
}

// ---------------------------------------------------------------------------
// bf16 MFMA conv for CIN=32 (level-3 convs: feed only `points`, bf16-safe).
// 64-site tile, 4 waves, wave w owns sites w*16..w*16+15. A staged in LDS
// (stride 40 bf16 -> 2-way max, free), B pre-packed in MFMA fragment order.
// ---------------------------------------------------------------------------
template<int NTL, bool IN_BF16, bool OUT_BF16>
__global__ __launch_bounds__(256)
void mfma_conv32(const void* __restrict__ fin,
                 const float* __restrict__ att,
                 const int* __restrict__ nbr,
                 const unsigned short* __restrict__ Wb,  // [27][NTL][64][8] bf16
                 void* __restrict__ outv,
                 int CO_real, int N)
{
    __shared__ unsigned short sA[64 * 40];

    const int tid  = threadIdx.x;
    const int lane = tid & 63;
    const int w    = tid >> 6;
    const int n0   = blockIdx.x * 64;

    const int grow = tid >> 2;   // gather row 0..63
    const int gseg = tid & 3;    // 8-channel segment

    int idx = (n0 + grow < N) ? nbr[(size_t)(n0 + grow) * 27] : -1;

    f32x4 acc[NTL];
#pragma unroll
    for (int nt = 0; nt < NTL; ++nt)
        acc[nt] = (f32x4){0.f, 0.f, 0.f, 0.f};

    for (int k = 0; k < 27; ++k) {
        __syncthreads();
        bf16x8 v = {0, 0, 0, 0, 0, 0, 0, 0};
        if (idx >= 0) {
            if constexpr (IN_BF16) {
                v = *reinterpret_cast<const bf16x8*>(
                        (const unsigned short*)fin + (size_t)idx * 32 + gseg * 8);
            } else {
                const float* src = (const float*)fin + (size_t)idx * 32 + gseg * 8;
                const float4 x = *reinterpret_cast<const float4*>(src);
                const float4 y = *reinterpret_cast<const float4*>(src + 4);
                const float a = (att != nullptr) ? att[idx] : 1.f;
                unsigned short t[8] = { f2bf(x.x * a), f2bf(x.y * a), f2bf(x.z * a), f2bf(x.w * a),
                                        f2bf(y.x * a), f2bf(y.y * a), f2bf(y.z * a), f2bf(y.w * a) };
                v = *reinterpret_cast<bf16x8*>(t);
            }
        }
        *reinterpret_cast<bf16x8*>(&sA[grow * 40 + gseg * 8]) = v;
        __syncthreads();
        if (k + 1 < 27)
            idx = (n0 + grow < N) ? nbr[(size_t)(n0 + grow) * 27 + (k + 1)] : -1;

        // A fragment: row = lane&15 (site), k-cols = (lane>>4)*8 + 0..7
        const bf16x8 a = *reinterpret_cast<const bf16x8*>(
            &sA[(w * 16 + (lane & 15)) * 40 + (lane >> 4) * 8]);
        const unsigned short* wk = Wb + (size_t)k * NTL * 512;
#pragma unroll
        for (int nt = 0; nt < NTL; ++nt) {
            const bf16x8 b = *reinterpret_cast<const bf16x8*>(wk + nt * 512 + lane * 8);
            acc[nt] = __builtin_amdgcn_mfma_f32_16x16x32_bf16(a, b, acc[nt], 0, 0, 0);
        }
    }

    // D: col = lane&15, row = (lane>>4)*4 + j
    const int col = lane & 15;
    const int rg  = lane >> 4;
#pragma unroll
    for (int nt = 0; nt < NTL; ++nt) {
#pragma unroll
        for (int j = 0; j < 4; ++j) {
            const int n  = n0 + w * 16 + rg * 4 + j;
            const int co = nt * 16 + col;
            if (n < N && co < CO_real) {
                if constexpr (OUT_BF16)
                    ((unsigned short*)outv)[(size_t)n * CO_real + co] = f2bf(acc[nt][j]);
                else
                    ((float*)outv)[(size_t)n * CO_real + co] = acc[nt][j];
            }
        }
    }
}

// ---------------------------------------------------------------------------
// Score conv (CO=2): wave per site, lanes over channels, shuffle reduce.
// ---------------------------------------------------------------------------
template<int C>
__global__ __launch_bounds__(256)
void score_kernel(const float* __restrict__ x,
                  const int* __restrict__ nbr,
                  const float* __restrict__ W,       // [27, C, 2]
                  const int* __restrict__ coords,    // [N, 4]
                  float* __restrict__ ppn,           // [N, 6]
                  int N)
{
    const int lane = threadIdx.x & 63;
    const int wid  = threadIdx.x >> 6;
    const int site = blockIdx.x * (blockDim.x >> 6) + wid;
    if (site >= N) return;

    float a0 = 0.f, a1 = 0.f;
    for (int k = 0; k < 27; ++k) {
        const int idx = nbr[(size_t)site * 27 + k];
        if (idx < 0) continue;
        const float* xr = x + (size_t)idx * C;
        const float* Wk = W + (size_t)k * C * 2;
#pragma unroll
        for (int ci0 = 0; ci0 < C; ci0 += 64) {
            const int ci = ci0 + lane;
            if (C % 64 == 0 || ci < C) {
                const float xv = xr[ci];
                a0 = fmaf(xv, Wk[ci * 2 + 0], a0);
                a1 = fmaf(xv, Wk[ci * 2 + 1], a1);
            }
        }
    }
#pragma unroll
    for (int off = 32; off; off >>= 1) {
        a0 += __shfl_down(a0, off, 64);
        a1 += __shfl_down(a1, off, 64);
    }
    if (lane == 0) {
        ppn[(size_t)site * 6 + 4] = a0;
        ppn[(size_t)site * 6 + 5] = a1;
    }
    if (lane < 4) ppn[(size_t)site * 6 + lane] = (float)coords[(size_t)site * 4 + lane];
}

__global__ __launch_bounds__(256)
void att_kernel(const float* __restrict__ ppn, const int* __restrict__ parent,
                float* __restrict__ att, int N)
{
    const int i = blockIdx.x * blockDim.x + threadIdx.x;
    if (i >= N) return;
    const int p = parent[i];
    const float s0 = ppn[(size_t)p * 6 + 4];
    const float s1 = ppn[(size_t)p * 6 + 5];
    const float m  = fmaxf(s0, s1);
    const float e0 = expf(s0 - m);
    const float e1 = expf(s1 - m);
    const float p1 = e1 / (e0 + e1);
    att[i] = (p1 > 0.8f) ? 1.f : 0.f;
}

// Pack [27,32,{3,2,5}] heads into fp32 [27,32,10].
__global__ __launch_bounds__(256)
void pack_head_w(const float* __restrict__ wp, const float* __restrict__ ws,
                 const float* __restrict__ wt, float* __restrict__ Wh)
{
    const int i = blockIdx.x * blockDim.x + threadIdx.x;
    if (i >= 27 * 32 * 10) return;
    const int co = i % 10;
    const int ci = (i / 10) % 32;
    const int k  = i / 320;
    float v;
    if (co < 3)      v = wp[(k * 32 + ci) * 3 + co];
    else if (co < 5) v = ws[(k * 32 + ci) * 2 + (co - 3)];
    else             v = wt[(k * 32 + ci) * 5 + (co - 5)];
    Wh[i] = v;
}

// Pack fp32 W[27][32][CO_real] into bf16 MFMA B-fragment order
// Wb[k][nt][lane][j] = W[k][(lane>>4)*8+j][nt*16+(lane&15)]  (cols >= CO_real -> 0)
__global__ __launch_bounds__(256)
void pack_wb(const float* __restrict__ W, unsigned short* __restrict__ Wb,
             int CO_real, int NTL)
{
    const int t = blockIdx.x * blockDim.x + threadIdx.x;
    if (t >= 27 * NTL * 64) return;
    const int lane = t & 63;
    const int nt   = (t >> 6) % NTL;
    const int k    = t / (64 * NTL);
    const int co   = nt * 16 + (lane & 15);
#pragma unroll
    for (int j = 0; j < 8; ++j) {
        const int ci = (lane >> 4) * 8 + j;
        const float x = (co < CO_real) ? W[((size_t)k * 32 + ci) * CO_real + co] : 0.f;
        Wb[(size_t)t * 8 + j] = f2bf(x);
    }
}

extern "C" void kernel_launch(void* const* d_in, const int* in_sizes, int n_in,
                              void* d_out, int out_size, void* d_ws, size_t ws_size,
                              hipStream_t stream)
{
    const float* f1       = (const float*)d_in[0];
    const float* f2       = (const float*)d_in[1];
    const float* f3       = (const float*)d_in[2];
    const float* w1_conv  = (const float*)d_in[3];
    const float* w1_score = (const float*)d_in[4];
    const float* w2_conv  = (const float*)d_in[5];
    const float* w2_score = (const float*)d_in[6];
    const float* w3_conv  = (const float*)d_in[7];
    const float* w3_pix   = (const float*)d_in[8];
    const float* w3_score = (const float*)d_in[9];
    const float* w3_type  = (const float*)d_in[10];
    const int* coords1    = (const int*)d_in[11];
    const int* coords2    = (const int*)d_in[12];
    const int* nbr1       = (const int*)d_in[13];
    const int* nbr2       = (const int*)d_in[14];
    const int* nbr3       = (const int*)d_in[15];
    const int* parent12   = (const int*)d_in[16];
    const int* parent23   = (const int*)d_in[17];

    const int N1 = in_sizes[0] / 160;
    const int N2 = in_sizes[1] / 96;
    const int N3 = in_sizes[2] / 32;

    // Output layout: points[N3,10] | ppn1[N1,6] | ppn2[N2,6] | att[N2] | att2[N3]
    float* points = (float*)d_out;
    float* ppn1   = points + (size_t)N3 * 10;
    float* ppn2   = ppn1 + (size_t)N1 * 6;
    float* attn   = ppn2 + (size_t)N2 * 6;
    float* attn2  = attn + (size_t)N2;

    // Workspace: fp32 feature buffer (x -> y), then reused as bf16 z buffer.
    float* buf = (float*)d_ws;
    size_t bufElems = (size_t)N1 * 160;
    if ((size_t)N2 * 96 > bufElems) bufElems = (size_t)N2 * 96;
    if ((size_t)N3 * 32 > bufElems) bufElems = (size_t)N3 * 32;
    float* Whf          = buf + bufElems;             // [27*32*10] fp32
    unsigned short* Wb3 = (unsigned short*)(Whf + 27 * 32 * 10);  // [27*2*512]
    unsigned short* Wbh = Wb3 + 27 * 2 * 512;                     // [27*1*512]
    unsigned short* zbuf = (unsigned short*)buf;      // z as bf16, reuses buf

    pack_head_w<<<(27 * 32 * 10 + 255) / 256, 256, 0, stream>>>(w3_pix, w3_score, w3_type, Whf);
    pack_wb<<<(27 * 2 * 64 + 255) / 256, 256, 0, stream>>>(w3_conv, Wb3, 32, 2);
    pack_wb<<<(27 * 1 * 64 + 255) / 256, 256, 0, stream>>>(Whf, Wbh, 10, 1);

    // ---- level 1 (stride 4), fp32 ----
    subm_conv_kernel<160, 160, 32, 4, 4>
        <<<(N1 + 31) / 32, (160 / 4) * (32 / 4), 0, stream>>>(f1, nullptr, nbr1, w1_conv, buf, N1);
    score_kernel<160><<<(N1 + 3) / 4, 256, 0, stream>>>(buf, nbr1, w1_score, coords1, ppn1, N1);
    att_kernel<<<(N2 + 255) / 256, 256, 0, stream>>>(ppn1, parent12, attn, N2);

    // ---- level 2 (stride 2), fp32 ----
    subm_conv_kernel<96, 96, 64, 8, 4>
        <<<(N2 + 63) / 64, (96 / 4) * (64 / 8), 0, stream>>>(f2, attn, nbr2, w2_conv, buf, N2);
    score_kernel<96><<<(N2 + 3) / 4, 256, 0, stream>>>(buf, nbr2, w2_score, coords2, ppn2, N2);
    att_kernel<<<(N3 + 255) / 256, 256, 0, stream>>>(ppn2, parent23, attn2, N3);

    // ---- level 3 (full res), bf16 MFMA (feeds only `points`) ----
    mfma_conv32<2, false, true>
        <<<(N3 + 63) / 64, 256, 0, stream>>>(f3, attn2, nbr3, Wb3, zbuf, 32, N3);
    mfma_conv32<1, true, false>
        <<<(N3 + 63) / 64, 256, 0, stream>>>(zbuf, nullptr, nbr3, Wbh, points, 10, N3);
}

// Round 3
// 1332.995 us; speedup vs baseline: 1.8564x; 1.8034x over previous
//
#include <hip/hip_runtime.h>
#include <cstddef>

typedef _Float16 f16;
typedef f16 f16x4 __attribute__((ext_vector_type(4)));
typedef f16 f16x8 __attribute__((ext_vector_type(8)));
typedef float f32x4 __attribute__((ext_vector_type(4)));

// ---------------------------------------------------------------------------
// Generic MFMA submanifold conv (16x16x32 f16 MFMA).
//   SPLIT=true : fp16x2 Markidis split (hi + lo*2^12), 3 MFMAs/term pair,
//                ~fp32 accuracy -> safe for the mask-threshold chain.
//   SPLIT=false: single-term f16 (points chain only).
// Block = 256 thr = 4 waves, 64 sites; wave w owns sites w*16..w*16+15.
// A staged per-k in LDS (row stride = C halves, 16B aligned; b128 reads are
// <=8 addr/bank = throughput-optimal). B pre-packed in fragment order.
// Fragment maps HW-verified by round-2 passing kernel:
//   A: row=lane&15, k=(lane>>4)*8+j ; B: col=lane&15, k=(lane>>4)*8+j
//   D: col=lane&15, row=(lane>>4)*4+j
// ---------------------------------------------------------------------------
template<int C, int NTL, bool SPLIT, bool IN_F16, bool OUT_F16>
__global__ __launch_bounds__(256)
void mfma_conv(const void* __restrict__ finv,
               const float* __restrict__ att,    // nullable 0/1 row scale
               const int* __restrict__ nbr,      // [N,27]
               const f16* __restrict__ Wb,       // [27][C/32][NTL][TERMS][64][8]
               float* __restrict__ outf,
               f16* __restrict__ outh,
               int ostride, int ooff, int CO_real, int N)
{
    constexpr int KK    = C / 32;
    constexpr int TERMS = SPLIT ? 2 : 1;
    constexpr int PLANE = 64 * C;
    __shared__ f16 sA[PLANE * (SPLIT ? 2 : 1)];

    const int tid  = threadIdx.x;
    const int lane = tid & 63;
    const int w    = tid >> 6;
    const int n0   = blockIdx.x * 64;
    const int grow = tid >> 2;          // staging row (4 threads per row)
    const int gcol = tid & 3;

    int idx = (n0 + grow < N) ? nbr[(size_t)(n0 + grow) * 27] : -1;

    f32x4 acc[NTL];
    f32x4 acc2[NTL];                    // lo-terms, scaled 2^12 (DCE'd if !SPLIT)
#pragma unroll
    for (int nt = 0; nt < NTL; ++nt) {
        acc[nt]  = (f32x4){0.f, 0.f, 0.f, 0.f};
        acc2[nt] = (f32x4){0.f, 0.f, 0.f, 0.f};
    }

    for (int k = 0; k < 27; ++k) {
        // ---- stage A tile (zero row if neighbor absent; fuse att scale) ----
        if constexpr (IN_F16) {
#pragma unroll
            for (int i = 0; i < C / 32; ++i) {
                const int c8 = gcol + i * 4;
                f16x8 v = {};
                if (idx >= 0)
                    v = *(const f16x8*)((const f16*)finv + (size_t)idx * C + c8 * 8);
                *(f16x8*)&sA[grow * C + c8 * 8] = v;
            }
        } else {
            const float* fin = (const float*)finv;
            const float a = (att != nullptr && idx >= 0) ? att[idx] : 1.f;
#pragma unroll
            for (int i = 0; i < C / 16; ++i) {
                const int c4 = gcol + i * 4;
                float4 v = make_float4(0.f, 0.f, 0.f, 0.f);
                if (idx >= 0)
                    v = *(const float4*)(fin + (size_t)idx * C + c4 * 4);
                const float xs[4] = {v.x * a, v.y * a, v.z * a, v.w * a};
                f16x4 hi, lo;
#pragma unroll
                for (int j = 0; j < 4; ++j) {
                    const f16 h = (f16)xs[j];
                    hi[j] = h;
                    if constexpr (SPLIT)
                        lo[j] = (f16)((xs[j] - (float)h) * 4096.f);
                }
                *(f16x4*)&sA[grow * C + c4 * 4] = hi;
                if constexpr (SPLIT)
                    *(f16x4*)&sA[PLANE + grow * C + c4 * 4] = lo;
            }
        }
        __syncthreads();
        if (k + 1 < 27)  // prefetch next k's index; hides under MFMAs
            idx = (n0 + grow < N) ? nbr[(size_t)(n0 + grow) * 27 + (k + 1)] : -1;

        // ---- MFMA over K tiles ----
        const int arow = w * 16 + (lane & 15);
#pragma unroll
        for (int kk = 0; kk < KK; ++kk) {
            const f16x8 ah = *(const f16x8*)&sA[arow * C + kk * 32 + (lane >> 4) * 8];
            f16x8 al = {};
            if constexpr (SPLIT)
                al = *(const f16x8*)&sA[PLANE + arow * C + kk * 32 + (lane >> 4) * 8];
            const f16* wk = Wb + ((size_t)(k * KK + kk) * NTL * TERMS) * 512 + lane * 8;
#pragma unroll
            for (int nt = 0; nt < NTL; ++nt) {
                const f16x8 bh = *(const f16x8*)(wk + (size_t)nt * TERMS * 512);
                acc[nt] = __builtin_amdgcn_mfma_f32_16x16x32_f16(ah, bh, acc[nt], 0, 0, 0);
                if constexpr (SPLIT) {
                    const f16x8 bl = *(const f16x8*)(wk + (size_t)nt * TERMS * 512 + 512);
                    acc2[nt] = __builtin_amdgcn_mfma_f32_16x16x32_f16(ah, bl, acc2[nt], 0, 0, 0);
                    acc2[nt] = __builtin_amdgcn_mfma_f32_16x16x32_f16(al, bh, acc2[nt], 0, 0, 0);
                }
            }
        }
        __syncthreads();
    }

    // ---- epilogue: merge lo-terms, store ----
    const int col = lane & 15;
    const int rg  = lane >> 4;
#pragma unroll
    for (int nt = 0; nt < NTL; ++nt) {
#pragma unroll
        for (int j = 0; j < 4; ++j) {
            float r = acc[nt][j];
            if constexpr (SPLIT) r += acc2[nt][j] * (1.f / 4096.f);
            const int n  = n0 + w * 16 + rg * 4 + j;
            const int co = nt * 16 + col;
            if (n < N && co < CO_real) {
                if constexpr (OUT_F16)
                    outh[(size_t)n * ostride + ooff + co] = (f16)r;
                else
                    outf[(size_t)n * ostride + ooff + co] = r;
            }
        }
    }
}

// Pack fp32 W[27][C][CO_real] into f16 fragment order (hi term, then scaled lo).
__global__ __launch_bounds__(256)
void pack_w_f16(const float* __restrict__ W, f16* __restrict__ Wb,
                int C, int CO_real, int NTL, int TERMS)
{
    const int KK = C / 32;
    const int F  = 27 * KK * NTL * TERMS;
    const int t  = blockIdx.x * blockDim.x + threadIdx.x;
    if (t >= F * 64) return;
    const int lane = t & 63;
    const int f    = t >> 6;
    const int term = f % TERMS;
    const int nt   = (f / TERMS) % NTL;
    const int kk   = (f / (TERMS * NTL)) % KK;
    const int k    = f / (TERMS * NTL * KK);
    const int co   = nt * 16 + (lane & 15);
#pragma unroll
    for (int j = 0; j < 8; ++j) {
        const int ci = kk * 32 + (lane >> 4) * 8 + j;
        const float x = (co < CO_real) ? W[((size_t)k * C + ci) * CO_real + co] : 0.f;
        const f16 h = (f16)x;
        Wb[(size_t)t * 8 + j] = (term == 0) ? h : (f16)((x - (float)h) * 4096.f);
    }
}

// Pack [27,32,{3,2,5}] heads into fp32 [27,32,10].
__global__ __launch_bounds__(256)
void pack_head_w(const float* __restrict__ wp, const float* __restrict__ ws,
                 const float* __restrict__ wt, float* __restrict__ Wh)
{
    const int i = blockIdx.x * blockDim.x + threadIdx.x;
    if (i >= 27 * 32 * 10) return;
    const int co = i % 10;
    const int ci = (i / 10) % 32;
    const int k  = i / 320;
    float v;
    if (co < 3)      v = wp[(k * 32 + ci) * 3 + co];
    else if (co < 5) v = ws[(k * 32 + ci) * 2 + (co - 3)];
    else             v = wt[(k * 32 + ci) * 5 + (co - 5)];
    Wh[i] = v;
}

__global__ __launch_bounds__(256)
void coords_kernel(const int* __restrict__ coords, float* __restrict__ ppn, int N)
{
    const int i = blockIdx.x * blockDim.x + threadIdx.x;
    if (i < N * 4) ppn[(size_t)(i >> 2) * 6 + (i & 3)] = (float)coords[i];
}

__global__ __launch_bounds__(256)
void att_kernel(const float* __restrict__ ppn, const int* __restrict__ parent,
                float* __restrict__ att, int N)
{
    const int i = blockIdx.x * blockDim.x + threadIdx.x;
    if (i >= N) return;
    const int p = parent[i];
    const float s0 = ppn[(size_t)p * 6 + 4];
    const float s1 = ppn[(size_t)p * 6 + 5];
    const float m  = fmaxf(s0, s1);
    const float e0 = expf(s0 - m);
    const float e1 = expf(s1 - m);
    const float p1 = e1 / (e0 + e1);
    att[i] = (p1 > 0.8f) ? 1.f : 0.f;
}

extern "C" void kernel_launch(void* const* d_in, const int* in_sizes, int n_in,
                              void* d_out, int out_size, void* d_ws, size_t ws_size,
                              hipStream_t stream)
{
    const float* f1       = (const float*)d_in[0];
    const float* f2       = (const float*)d_in[1];
    const float* f3       = (const float*)d_in[2];
    const float* w1_conv  = (const float*)d_in[3];
    const float* w1_score = (const float*)d_in[4];
    const float* w2_conv  = (const float*)d_in[5];
    const float* w2_score = (const float*)d_in[6];
    const float* w3_conv  = (const float*)d_in[7];
    const float* w3_pix   = (const float*)d_in[8];
    const float* w3_score = (const float*)d_in[9];
    const float* w3_type  = (const float*)d_in[10];
    const int* coords1    = (const int*)d_in[11];
    const int* coords2    = (const int*)d_in[12];
    const int* nbr1       = (const int*)d_in[13];
    const int* nbr2       = (const int*)d_in[14];
    const int* nbr3       = (const int*)d_in[15];
    const int* parent12   = (const int*)d_in[16];
    const int* parent23   = (const int*)d_in[17];

    const int N1 = in_sizes[0] / 160;   // 20000
    const int N2 = in_sizes[1] / 96;    // 160000
    const int N3 = in_sizes[2] / 32;    // 320000

    // Output layout: points[N3,10] | ppn1[N1,6] | ppn2[N2,6] | att[N2] | att2[N3]
    float* points = (float*)d_out;
    float* ppn1   = points + (size_t)N3 * 10;
    float* ppn2   = ppn1 + (size_t)N1 * 6;
    float* attn   = ppn2 + (size_t)N2 * 6;
    float* attn2  = attn + (size_t)N2;

    // Workspace layout. Lifetimes: x (conv1->score1), y (conv2->score2),
    // z (conv3->head, reuses y's region as f16).
    float* x   = (float*)d_ws;                         // N1*160 fp32
    float* y   = x + (size_t)N1 * 160;                 // N2*96  fp32
    f16*   z   = (f16*)y;                              // N3*32  f16 (after y dead)
    float* Whf = y + (size_t)N2 * 96;                  // 27*32*10 fp32
    f16* Wb1 = (f16*)(Whf + 27 * 32 * 10);             // [27][5][10][2][512]
    f16* Ws1 = Wb1 + (size_t)27 * 5 * 10 * 2 * 512;    // [27][5][1][2][512]
    f16* Wb2 = Ws1 + (size_t)27 * 5 * 1 * 2 * 512;     // [27][3][6][2][512]
    f16* Ws2 = Wb2 + (size_t)27 * 3 * 6 * 2 * 512;     // [27][3][1][2][512]
    f16* Wb3 = Ws2 + (size_t)27 * 3 * 1 * 2 * 512;     // [27][1][2][1][512]
    f16* Wbh = Wb3 + (size_t)27 * 1 * 2 * 1 * 512;     // [27][1][1][1][512]

    // ---- weight packing ----
    pack_head_w<<<(27 * 32 * 10 + 255) / 256, 256, 0, stream>>>(w3_pix, w3_score, w3_type, Whf);
    pack_w_f16<<<(27 * 5 * 10 * 2 * 64 + 255) / 256, 256, 0, stream>>>(w1_conv, Wb1, 160, 160, 10, 2);
    pack_w_f16<<<(27 * 5 * 1 * 2 * 64 + 255) / 256, 256, 0, stream>>>(w1_score, Ws1, 160, 2, 1, 2);
    pack_w_f16<<<(27 * 3 * 6 * 2 * 64 + 255) / 256, 256, 0, stream>>>(w2_conv, Wb2, 96, 96, 6, 2);
    pack_w_f16<<<(27 * 3 * 1 * 2 * 64 + 255) / 256, 256, 0, stream>>>(w2_score, Ws2, 96, 2, 1, 2);
    pack_w_f16<<<(27 * 1 * 2 * 1 * 64 + 255) / 256, 256, 0, stream>>>(w3_conv, Wb3, 32, 32, 2, 1);
    pack_w_f16<<<(27 * 1 * 1 * 1 * 64 + 255) / 256, 256, 0, stream>>>(Whf, Wbh, 32, 10, 1, 1);

    coords_kernel<<<(N1 * 4 + 255) / 256, 256, 0, stream>>>(coords1, ppn1, N1);
    coords_kernel<<<(N2 * 4 + 255) / 256, 256, 0, stream>>>(coords2, ppn2, N2);

    // ---- level 1 ----
    mfma_conv<160, 10, true, false, false><<<(N1 + 63) / 64, 256, 0, stream>>>(
        f1, nullptr, nbr1, Wb1, x, nullptr, 160, 0, 160, N1);
    mfma_conv<160, 1, true, false, false><<<(N1 + 63) / 64, 256, 0, stream>>>(
        x, nullptr, nbr1, Ws1, ppn1, nullptr, 6, 4, 2, N1);
    att_kernel<<<(N2 + 255) / 256, 256, 0, stream>>>(ppn1, parent12, attn, N2);

    // ---- level 2 ----
    mfma_conv<96, 6, true, false, false><<<(N2 + 63) / 64, 256, 0, stream>>>(
        f2, attn, nbr2, Wb2, y, nullptr, 96, 0, 96, N2);
    mfma_conv<96, 1, true, false, false><<<(N2 + 63) / 64, 256, 0, stream>>>(
        y, nullptr, nbr2, Ws2, ppn2, nullptr, 6, 4, 2, N2);
    att_kernel<<<(N3 + 255) / 256, 256, 0, stream>>>(ppn2, parent23, attn2, N3);

    // ---- level 3 (points chain, single-term f16) ----
    mfma_conv<32, 2, false, false, true><<<(N3 + 63) / 64, 256, 0, stream>>>(
        f3, attn2, nbr3, Wb3, nullptr, z, 32, 0, 32, N3);
    mfma_conv<32, 1, false, true, false><<<(N3 + 63) / 64, 256, 0, stream>>>(
        z, nullptr, nbr3, Wbh, points, nullptr, 10, 0, 10, N3);
}